// Round 1
// baseline (371.897 us; speedup 1.0000x reference)
//
#include <hip/hip_runtime.h>

#define TT 24
#define NN 1000
#define DD 64

__global__ __launch_bounds__(256)
void stgcn_fused(const float* __restrict__ x,
                 const float* __restrict__ w1, const float* __restrict__ b1,
                 const float* __restrict__ w2, const float* __restrict__ b2,
                 const float* __restrict__ gamma, const float* __restrict__ beta,
                 float* __restrict__ out)
{
    const int lane = threadIdx.x & 63;
    const int wv   = threadIdx.x >> 6;
    const int b    = blockIdx.x / 250;        // 250 node-groups of 4
    const int n    = (blockIdx.x % 250) * 4 + wv;   // exact: 250*4 = 1000

    // Per-lane weight rows (output channel = lane), 0.5 window-average folded in.
    float w1r[DD], w2r[DD];
#pragma unroll
    for (int q = 0; q < DD / 4; ++q) {
        float4 v1 = *reinterpret_cast<const float4*>(&w1[lane * DD + q * 4]);
        float4 v2 = *reinterpret_cast<const float4*>(&w2[lane * DD + q * 4]);
        w1r[q*4+0] = 0.5f * v1.x; w1r[q*4+1] = 0.5f * v1.y;
        w1r[q*4+2] = 0.5f * v1.z; w1r[q*4+3] = 0.5f * v1.w;
        w2r[q*4+0] = 0.5f * v2.x; w2r[q*4+1] = 0.5f * v2.y;
        w2r[q*4+2] = 0.5f * v2.z; w2r[q*4+3] = 0.5f * v2.w;
    }
    const float bi1 = b1[lane], bi2 = b2[lane];
    const float ga  = gamma[lane], be = beta[lane];

    __shared__ __align__(16) float as[4][DD];   // per-wave broadcast buffer

    const size_t rowstride = (size_t)NN * DD;   // stride between consecutive t
    const float* xp = x   + ((size_t)b * TT * NN + n) * DD + lane;
    float*       op = out + ((size_t)b * TT * NN + n) * DD + lane;

    float xc    = xp[0];     // x[b, 0, n, lane]
    float xprev = 0.0f;      // zero-pad at t = -1
    for (int t = 0; t < TT; ++t) {
        // prefetch next timestep's element while we compute this one
        float xn = (t + 1 < TT) ? xp[(size_t)(t + 1) * rowstride] : 0.0f;

        float a = xprev + xc;          // 2*avg; 0.5 folded into weights
        as[wv][lane] = a;
        __syncthreads();

        float h1a = 0.f, h1b = 0.f, h2a = 0.f, h2b = 0.f;
#pragma unroll
        for (int q = 0; q < DD / 4; ++q) {
            float4 av = *reinterpret_cast<const float4*>(&as[wv][q * 4]); // uniform addr → broadcast
            h1a = fmaf(w1r[q*4+0], av.x, h1a);
            h2a = fmaf(w2r[q*4+0], av.x, h2a);
            h1b = fmaf(w1r[q*4+1], av.y, h1b);
            h2b = fmaf(w2r[q*4+1], av.y, h2b);
            h1a = fmaf(w1r[q*4+2], av.z, h1a);
            h2a = fmaf(w2r[q*4+2], av.z, h2a);
            h1b = fmaf(w1r[q*4+3], av.w, h1b);
            h2b = fmaf(w2r[q*4+3], av.w, h2b);
        }
        __syncthreads();   // reads done before next iteration's overwrite

        float h1 = h1a + h1b + bi1;
        float h2 = h2a + h2b + bi2;
        float p  = h1 * h2;
        float o  = (p > 0.f ? p : 0.f) + h1 + xc;

        // LayerNorm over the 64 lanes (d-axis)
        float s = o, s2 = o * o;
#pragma unroll
        for (int off = 32; off > 0; off >>= 1) {
            s  += __shfl_xor(s,  off, 64);
            s2 += __shfl_xor(s2, off, 64);
        }
        float mu  = s  * (1.0f / 64.0f);
        float var = s2 * (1.0f / 64.0f) - mu * mu;
        float y = (o - mu) * rsqrtf(var + 1e-5f) * ga + be;

        op[(size_t)t * rowstride] = y;

        xprev = xc;
        xc = xn;
    }
}

extern "C" void kernel_launch(void* const* d_in, const int* in_sizes, int n_in,
                              void* d_out, int out_size, void* d_ws, size_t ws_size,
                              hipStream_t stream) {
    const float* x     = (const float*)d_in[0];
    // d_in[1] = adj — dead in the reference (overwritten by tiled identity)
    const float* w1    = (const float*)d_in[2];
    const float* b1    = (const float*)d_in[3];
    const float* w2    = (const float*)d_in[4];
    const float* b2    = (const float*)d_in[5];
    const float* gamma = (const float*)d_in[6];
    const float* beta  = (const float*)d_in[7];
    float* out = (float*)d_out;

    dim3 grid(32 * 250);   // B * (N/4)
    dim3 block(256);       // 4 waves, 1 node per wave
    hipLaunchKernelGGL(stgcn_fused, grid, block, 0, stream,
                       x, w1, b1, w2, b2, gamma, beta, out);
}

// Round 2
// 90.631 us; speedup vs baseline: 4.1034x; 4.1034x over previous
//
#include <hip/hip_runtime.h>
#include <hip/hip_bf16.h>

#define TT 24
#define NN 1000
#define DD 64
#define TCH 12                 // timesteps per block
#define ROWS 64                // node rows per block tile
#define LDSW (ROWS * DD)       // f32 words per LDS buffer (4096)

typedef short bf16x8 __attribute__((ext_vector_type(8)));
typedef float f32x4  __attribute__((ext_vector_type(4)));

__device__ __forceinline__ short f2bf(float f) {
    __hip_bfloat16 h = __float2bfloat16(f);
    return *reinterpret_cast<short*>(&h);
}

__global__ __launch_bounds__(256)
void stgcn_mfma(const float* __restrict__ x,
                const float* __restrict__ w1, const float* __restrict__ b1,
                const float* __restrict__ w2, const float* __restrict__ b2,
                const float* __restrict__ gamma, const float* __restrict__ beta,
                float* __restrict__ out)
{
    const int tid = threadIdx.x;
    const int l   = tid & 63;
    const int wv  = tid >> 6;      // wave id 0..3 (16-row m-tile each)
    const int lr  = l & 15;        // A-row / C-col within 16
    const int lc  = l >> 4;        // 0..3

    const int bid   = blockIdx.x;
    const int tc    = bid & 1;
    const int ntile = (bid >> 1) & 15;
    const int b     = bid >> 5;
    const int t0    = tc * TCH;
    const int n0    = ntile * ROWS;

    __shared__ float xs[2][LDSW];   // 32 KB, double-buffered x tile (swizzled)

    // ---- persistent B-fragments: B[k][d] = 0.5*w[d][k], d = lr+16nf, k = lc*8+j+32ks
    bf16x8 B1[4][2], B2[4][2];
#pragma unroll
    for (int nf = 0; nf < 4; ++nf) {
#pragma unroll
        for (int ks = 0; ks < 2; ++ks) {
            const float* p1 = &w1[(size_t)(lr + 16*nf) * DD + lc*8 + 32*ks];
            const float* p2 = &w2[(size_t)(lr + 16*nf) * DD + lc*8 + 32*ks];
            f32x4 u0 = *(const f32x4*)p1, u1 = *(const f32x4*)(p1 + 4);
            f32x4 v0 = *(const f32x4*)p2, v1 = *(const f32x4*)(p2 + 4);
#pragma unroll
            for (int j = 0; j < 4; ++j) {
                B1[nf][ks][j]     = f2bf(0.5f * u0[j]);
                B1[nf][ks][4 + j] = f2bf(0.5f * u1[j]);
                B2[nf][ks][j]     = f2bf(0.5f * v0[j]);
                B2[nf][ks][4 + j] = f2bf(0.5f * v1[j]);
            }
        }
    }
    float bia1[4], bia2[4], gam[4], bet[4];
#pragma unroll
    for (int nf = 0; nf < 4; ++nf) {
        bia1[nf] = b1[lr + 16*nf];
        bia2[nf] = b2[lr + 16*nf];
        gam[nf]  = gamma[lr + 16*nf];
        bet[nf]  = beta[lr + 16*nf];
    }

    // ---- staging geometry: thread covers rows sr0+16r, 16B column sc, 4 rounds
    const int sr0   = tid >> 4;          // 0..15
    const int sc    = (tid & 15) * 4;    // word col, 4-aligned
    const int smask = (sr0 & 7) << 2;    // swizzle mask (const across rounds)
    int gr_[4], swoff_[4];
#pragma unroll
    for (int r = 0; r < 4; ++r) {
        int row = sr0 + 16*r;
        gr_[r]    = min(n0 + row, NN - 1);          // clamp tail tile
        swoff_[r] = row*DD + (sc ^ smask);          // swizzled LDS word offset
    }

    // ---- A-frag geometry: row = wv*16+lr, k = lc*8+j+32ks
    const int arow  = wv*16 + lr;
    const int amask = (arow & 7) << 2;
    const int agrow = min(n0 + arow, NN - 1);       // clamped global row

    // ---- x_prev A-layout values (f32). t0==0 -> zero pad.
    float xp[16];
    if (t0 > 0) {
        const float* pg = x + ((size_t)(b*TT + (t0-1)) * NN + agrow) * DD;
        f32x4 q0 = *(const f32x4*)(pg + lc*8);
        f32x4 q1 = *(const f32x4*)(pg + lc*8 + 4);
        f32x4 q2 = *(const f32x4*)(pg + lc*8 + 32);
        f32x4 q3 = *(const f32x4*)(pg + lc*8 + 36);
#pragma unroll
        for (int j = 0; j < 4; ++j) {
            xp[j]      = q0[j];
            xp[4 + j]  = q1[j];
            xp[8 + j]  = q2[j];
            xp[12 + j] = q3[j];
        }
    } else {
#pragma unroll
        for (int j = 0; j < 16; ++j) xp[j] = 0.f;
    }

    // ---- prologue: stage x[t0] into xs[0]
    {
        const size_t bt = (size_t)(b*TT + t0) * NN * DD;
#pragma unroll
        for (int r = 0; r < 4; ++r) {
            f32x4 v = *(const f32x4*)(x + bt + (size_t)gr_[r]*DD + sc);
            *(f32x4*)&xs[0][swoff_[r]] = v;
        }
    }
    __syncthreads();

    int cur = 0;
    for (int t = t0; t < t0 + TCH; ++t) {
        // 1) issue next-t loads early (hide HBM latency under compute)
        const bool hasn = (t + 1 < t0 + TCH);
        f32x4 st0, st1, st2, st3;
        if (hasn) {
            const size_t bt = (size_t)(b*TT + (t+1)) * NN * DD;
            st0 = *(const f32x4*)(x + bt + (size_t)gr_[0]*DD + sc);
            st1 = *(const f32x4*)(x + bt + (size_t)gr_[1]*DD + sc);
            st2 = *(const f32x4*)(x + bt + (size_t)gr_[2]*DD + sc);
            st3 = *(const f32x4*)(x + bt + (size_t)gr_[3]*DD + sc);
        }

        // 2) read x_t A-frags from LDS, build a = x_t + x_prev in bf16
        const float* bufc = xs[cur];
        float xt[16];
#pragma unroll
        for (int ks = 0; ks < 2; ++ks) {
#pragma unroll
            for (int h = 0; h < 2; ++h) {
                const int cw = lc*8 + 32*ks + 4*h;
                f32x4 v = *(const f32x4*)&bufc[arow*DD + (cw ^ amask)];
#pragma unroll
                for (int j = 0; j < 4; ++j) xt[ks*8 + h*4 + j] = v[j];
            }
        }
        bf16x8 A[2];
#pragma unroll
        for (int ks = 0; ks < 2; ++ks) {
#pragma unroll
            for (int j = 0; j < 8; ++j) {
                A[ks][j] = f2bf(xt[ks*8 + j] + xp[ks*8 + j]);
                xp[ks*8 + j] = xt[ks*8 + j];
            }
        }

        // 3) MFMA: h = a @ (0.5*w^T), K=64
        f32x4 C1[4], C2[4];
#pragma unroll
        for (int nf = 0; nf < 4; ++nf) { C1[nf] = 0; C2[nf] = 0; }
#pragma unroll
        for (int nf = 0; nf < 4; ++nf) {
#pragma unroll
            for (int ks = 0; ks < 2; ++ks) {
                C1[nf] = __builtin_amdgcn_mfma_f32_16x16x32_bf16(A[ks], B1[nf][ks], C1[nf], 0, 0, 0);
                C2[nf] = __builtin_amdgcn_mfma_f32_16x16x32_bf16(A[ks], B2[nf][ks], C2[nf], 0, 0, 0);
            }
        }

        // 4) epilogue: bias, gate, residual, LayerNorm, store
        const size_t obase = ((size_t)(b*TT + t) * NN + n0) * DD;
        float o[4][4], s[4], s2[4];
#pragma unroll
        for (int i = 0; i < 4; ++i) { s[i] = 0.f; s2[i] = 0.f; }
#pragma unroll
        for (int i = 0; i < 4; ++i) {
            const int rowe = wv*16 + lc*4 + i;
            const int em   = (rowe & 7) << 2;
#pragma unroll
            for (int nf = 0; nf < 4; ++nf) {
                const int cole = lr + 16*nf;
                float xres = bufc[rowe*DD + (cole ^ em)];
                float h1 = C1[nf][i] + bia1[nf];
                float h2 = C2[nf][i] + bia2[nf];
                float p  = h1 * h2;
                float oo = (p > 0.f ? p : 0.f) + h1 + xres;
                o[i][nf] = oo;
                s[i]  += oo;
                s2[i] += oo * oo;
            }
        }
#pragma unroll
        for (int off = 8; off >= 1; off >>= 1) {
#pragma unroll
            for (int i = 0; i < 4; ++i) {
                s[i]  += __shfl_xor(s[i],  off, 64);
                s2[i] += __shfl_xor(s2[i], off, 64);
            }
        }
#pragma unroll
        for (int i = 0; i < 4; ++i) {
            const int rowe = wv*16 + lc*4 + i;
            float mu = s[i] * (1.f/64.f);
            float va = s2[i] * (1.f/64.f) - mu*mu;
            float rs = rsqrtf(va + 1e-5f);
            if (n0 + rowe < NN) {
#pragma unroll
                for (int nf = 0; nf < 4; ++nf) {
                    const int cole = lr + 16*nf;
                    out[obase + (size_t)rowe*DD + cole] =
                        (o[i][nf] - mu) * rs * gam[nf] + bet[nf];
                }
            }
        }

        // 5) commit staged x[t+1] into the other buffer; one barrier per iter
        if (hasn) {
            float* bufn = xs[cur ^ 1];
            *(f32x4*)&bufn[swoff_[0]] = st0;
            *(f32x4*)&bufn[swoff_[1]] = st1;
            *(f32x4*)&bufn[swoff_[2]] = st2;
            *(f32x4*)&bufn[swoff_[3]] = st3;
        }
        __syncthreads();
        cur ^= 1;
    }
}

extern "C" void kernel_launch(void* const* d_in, const int* in_sizes, int n_in,
                              void* d_out, int out_size, void* d_ws, size_t ws_size,
                              hipStream_t stream) {
    const float* x     = (const float*)d_in[0];
    // d_in[1] = adj — dead in the reference (overwritten by tiled identity)
    const float* w1    = (const float*)d_in[2];
    const float* b1    = (const float*)d_in[3];
    const float* w2    = (const float*)d_in[4];
    const float* b2    = (const float*)d_in[5];
    const float* gamma = (const float*)d_in[6];
    const float* beta  = (const float*)d_in[7];
    float* out = (float*)d_out;

    dim3 grid(32 * 16 * 2);   // b * ntile * tchunk = 1024 blocks
    dim3 block(256);          // 4 waves
    hipLaunchKernelGGL(stgcn_mfma, grid, block, 0, stream,
                       x, w1, b1, w2, b2, gamma, beta, out);
}